// Round 2
// baseline (409042.236 us; speedup 1.0000x reference)
//
#include <hip/hip_runtime.h>

typedef __attribute__((ext_vector_type(4))) float f32x4;
typedef __attribute__((ext_vector_type(8))) short short8;
typedef unsigned int u32;
typedef unsigned short u16;

#define T_SEQ 4096
#define HDIM  2048
#define GDIM  8192   // 4*H
#define INDIM 512
#define NBLK  256    // recurrence blocks
#define FLAG_STRIDE 32  // ints -> 128B per flag line

__device__ __forceinline__ u16 f2bf(float x) {
  u32 u = __float_as_uint(x);
  return (u16)((u + 0x7fffu + ((u >> 16) & 1u)) >> 16);  // RNE
}

// ---------------- prep kernels ----------------
__global__ void k_zero_f32(float* __restrict__ p, int n) {
  int i = blockIdx.x * blockDim.x + threadIdx.x;
  int st = gridDim.x * blockDim.x;
  for (; i < n; i += st) p[i] = 0.f;
}

__global__ void k_bias_sum(const float* __restrict__ a, const float* __restrict__ b,
                           float* __restrict__ o, int n) {
  int i = blockIdx.x * blockDim.x + threadIdx.x;
  if (i < n) o[i] = a[i] + b[i];
}

__global__ void k_cvt_bf16(const float* __restrict__ in, u16* __restrict__ out, int n) {
  int i = blockIdx.x * blockDim.x + threadIdx.x;
  int st = gridDim.x * blockDim.x;
  for (; i < n; i += st) out[i] = f2bf(in[i]);
}

// ---------------- bf16 MFMA GEMM:  C[M,N] = A[M,K] * B[N,K]^T + bias[N] ----------------
// 128x128 tile, BK=64, 4 waves (2x2 quadrants of 64x64), 16x16x32 MFMA,
// XOR-swizzled LDS (slot ^= row&7) to kill the stride-128B bank conflict (G4/T2).
__global__ __launch_bounds__(256) void gemm_bt_bias(
    const u16* __restrict__ A, const u16* __restrict__ B,
    const float* __restrict__ bias, float* __restrict__ C,
    int M, int N, int K)
{
  __shared__ u16 As[128 * 64];
  __shared__ u16 Bs[128 * 64];
  const int tid = threadIdx.x;
  const int m0 = blockIdx.y * 128;
  const int n0 = blockIdx.x * 128;
  const int w = tid >> 6;
  const int lane = tid & 63;
  const int wm = (w >> 1) * 64, wn = (w & 1) * 64;
  const int lr = lane & 15, lk = lane >> 4;

  f32x4 acc[4][4];
  f32x4 zero = {0.f, 0.f, 0.f, 0.f};
#pragma unroll
  for (int i = 0; i < 4; ++i) {
#pragma unroll
    for (int j = 0; j < 4; ++j) acc[i][j] = zero;
  }

  const int r = tid >> 1;           // 0..127 (tile row)
  const int sbase = (tid & 1) * 4;  // slot base (each slot = 8 bf16 = 16B)

  for (int kt = 0; kt < K; kt += 64) {
    const u16* ga = A + (size_t)(m0 + r) * K + kt + sbase * 8;
    const u16* gb = B + (size_t)(n0 + r) * K + kt + sbase * 8;
    uint4 va[4], vb[4];
#pragma unroll
    for (int s = 0; s < 4; ++s) {
      va[s] = *reinterpret_cast<const uint4*>(ga + s * 8);
      vb[s] = *reinterpret_cast<const uint4*>(gb + s * 8);
    }
    __syncthreads();  // previous iter's reads done before overwrite
#pragma unroll
    for (int s = 0; s < 4; ++s) {
      int ps = (sbase + s) ^ (r & 7);
      *reinterpret_cast<uint4*>(&As[r * 64 + ps * 8]) = va[s];
      *reinterpret_cast<uint4*>(&Bs[r * 64 + ps * 8]) = vb[s];
    }
    __syncthreads();
#pragma unroll
    for (int k32 = 0; k32 < 2; ++k32) {
      short8 af[4], bg[4];
#pragma unroll
      for (int i = 0; i < 4; ++i) {
        int arow = wm + i * 16 + lr;
        int aslot = (k32 * 4 + lk) ^ (arow & 7);
        af[i] = *reinterpret_cast<const short8*>(&As[arow * 64 + aslot * 8]);
        int brow = wn + i * 16 + lr;
        int bslot = (k32 * 4 + lk) ^ (brow & 7);
        bg[i] = *reinterpret_cast<const short8*>(&Bs[brow * 64 + bslot * 8]);
      }
#pragma unroll
      for (int i = 0; i < 4; ++i) {
#pragma unroll
        for (int j = 0; j < 4; ++j) {
          acc[i][j] = __builtin_amdgcn_mfma_f32_16x16x32_bf16(af[i], bg[j], acc[i][j], 0, 0, 0);
        }
      }
    }
  }

  // epilogue: C/D layout col = lane&15, row = (lane>>4)*4 + reg  [m89-verified]
#pragma unroll
  for (int j = 0; j < 4; ++j) {
    int gcol = n0 + wn + j * 16 + lr;
    float bv = bias[gcol];
#pragma unroll
    for (int i = 0; i < 4; ++i) {
      int grow = m0 + wm + i * 16 + lk * 4;
#pragma unroll
      for (int rr = 0; rr < 4; ++rr) {
        C[(size_t)(grow + rr) * N + gcol] = acc[i][j][rr] + bv;
      }
    }
  }
}

// ---------------- persistent LSTM recurrence ----------------
// 256 blocks x 512 threads. Block owns h[bid*8 .. bid*8+8) -> 32 gate rows.
// W_hh rows held register-resident fp32 (128 VGPR/lane), pinned via asm so the
// compiler cannot rematerialize the loads (round-1 failure: VGPR=80, weights
// re-streamed from L2/L3 every step -> 256 GB -> 160 ms).
// Per step: each thread acquire-polls ITS OWN producer's flag (thread tid
// stages h[4*tid..4*tid+4), produced by block tid/2) -> stage h into LDS ->
// 32 dots (16 lanes/row) -> shfl reduce -> lanes 0-7 compute gates (c in lane
// registers) and store h (one wave => release store's vmcnt drain orders it)
// -> lane 0 release-stores flag = t+1.
__global__ __launch_bounds__(512, 2) void lstm_rec(
    const float* __restrict__ gx,    // [T][8192] precomputed input contribution (+biases)
    const float* __restrict__ Whh,   // [8192][2048] fp32
    float* __restrict__ hhist,       // [T+1][2048], row 0 pre-zeroed
    u16* __restrict__ hbf,           // [T][2048] bf16 copy of outputs, or nullptr
    int* __restrict__ flags,         // [NBLK*FLAG_STRIDE], pre-zeroed
    int T)
{
  const int tid = threadIdx.x;
  const int bid = blockIdx.x;
  const int sub = tid & 15;        // k-splitter within a row (16 per row)
  const int row_local = tid >> 4;  // 0..31
  const int q = row_local >> 3, jj = row_local & 7;
  const int grow = q * HDIM + bid * 8 + jj;  // global gate row

  // register-resident weight slice: k = sub*4 + 64*i, i=0..31 (float4 chunks)
  float4 wreg[32];
  const float* wrow = Whh + (size_t)grow * HDIM + sub * 4;
#pragma unroll
  for (int i = 0; i < 32; ++i) wreg[i] = *reinterpret_cast<const float4*>(wrow + 64 * i);
  // pin: values become asm outputs -> cannot be rematerialized as loads
#pragma unroll
  for (int i = 0; i < 32; ++i) {
    asm volatile("" : "+v"(wreg[i].x), "+v"(wreg[i].y), "+v"(wreg[i].z), "+v"(wreg[i].w));
  }

  __shared__ float h_lds[HDIM];
  __shared__ float gg[32];

  int* myflag = &flags[(tid >> 1) * FLAG_STRIDE];  // producer of h[4*tid .. 4*tid+4)
  float c = 0.f;  // cell state, live in lanes 0..7 only

  for (int t = 0; t < T; ++t) {
    // prefetch gx early (independent of h); stays in flight across the poll
    float gxv = 0.f;
    if (sub == 0) gxv = gx[(size_t)t * GDIM + grow];

    // wait for MY producer of h[t] (acquire pairs with its release)
    while (__hip_atomic_load(myflag, __ATOMIC_ACQUIRE, __HIP_MEMORY_SCOPE_AGENT) < t) {
    }
    __syncthreads();

    // stage h[t] into LDS (8KB, coalesced float4)
    const float* hrow = hhist + (size_t)t * HDIM;
    *reinterpret_cast<float4*>(&h_lds[tid * 4]) =
        *reinterpret_cast<const float4*>(hrow + tid * 4);
    __syncthreads();

    // dot: 128 MACs/lane, 4 independent accumulators
    f32x4 a = {0.f, 0.f, 0.f, 0.f};
#pragma unroll
    for (int i = 0; i < 32; ++i) {
      float4 hv = *reinterpret_cast<const float4*>(&h_lds[sub * 4 + 64 * i]);
      a.x += wreg[i].x * hv.x;
      a.y += wreg[i].y * hv.y;
      a.z += wreg[i].z * hv.z;
      a.w += wreg[i].w * hv.w;
    }
    float acc = (a.x + a.y) + (a.z + a.w);
    acc += __shfl_xor(acc, 8, 16);
    acc += __shfl_xor(acc, 4, 16);
    acc += __shfl_xor(acc, 2, 16);
    acc += __shfl_xor(acc, 1, 16);
    if (sub == 0) gg[row_local] = acc + gxv;
    __syncthreads();

    // gates (PyTorch order i,f,g,o) for the block's 8 h elements; lanes 0-7
    // (single wave -> the stores below are one instruction each; the release
    // store by lane 0 drains vmcnt first, ordering them)
    if (tid < 8) {
      float gi = gg[tid], gf = gg[8 + tid], gc = gg[16 + tid], go = gg[24 + tid];
      float i_ = 1.f / (1.f + expf(-gi));
      float f_ = 1.f / (1.f + expf(-gf));
      float g_ = tanhf(gc);
      float o_ = 1.f / (1.f + expf(-go));
      c = f_ * c + i_ * g_;
      float hval = o_ * tanhf(c);
      hhist[(size_t)(t + 1) * HDIM + bid * 8 + tid] = hval;
      if (hbf) hbf[(size_t)t * HDIM + bid * 8 + tid] = f2bf(hval);
    }
    if (tid == 0) {
      __hip_atomic_store(&flags[bid * FLAG_STRIDE], t + 1, __ATOMIC_RELEASE,
                         __HIP_MEMORY_SCOPE_AGENT);
    }
  }
}

// ---------------- heads: two 2048-dots ----------------
__global__ void k_heads(const float* __restrict__ h, const float* __restrict__ wt,
                        const float* __restrict__ bt, const float* __restrict__ wf,
                        const float* __restrict__ bfp, float* __restrict__ out) {
  int tid = threadIdx.x;  // 256
  float st = 0.f, sf = 0.f;
  for (int i = tid; i < HDIM; i += 256) {
    float hv = h[i];
    st += hv * wt[i];
    sf += hv * wf[i];
  }
#pragma unroll
  for (int m = 32; m >= 1; m >>= 1) {
    st += __shfl_xor(st, m, 64);
    sf += __shfl_xor(sf, m, 64);
  }
  __shared__ float ra[4], rb[4];
  if ((tid & 63) == 0) { ra[tid >> 6] = st; rb[tid >> 6] = sf; }
  __syncthreads();
  if (tid == 0) {
    out[0] = ra[0] + ra[1] + ra[2] + ra[3] + bt[0];
    out[1] = rb[0] + rb[1] + rb[2] + rb[3] + bfp[0];
  }
}

// ---------------- launch ----------------
extern "C" void kernel_launch(void* const* d_in, const int* in_sizes, int n_in,
                              void* d_out, int out_size, void* d_ws, size_t ws_size,
                              hipStream_t stream) {
  const float* x     = (const float*)d_in[0];
  const float* w_ih0 = (const float*)d_in[1];
  const float* w_hh0 = (const float*)d_in[2];
  const float* b_ih0 = (const float*)d_in[3];
  const float* b_hh0 = (const float*)d_in[4];
  const float* w_ih1 = (const float*)d_in[5];
  const float* w_hh1 = (const float*)d_in[6];
  const float* b_ih1 = (const float*)d_in[7];
  const float* b_hh1 = (const float*)d_in[8];
  const float* w_t   = (const float*)d_in[9];
  const float* b_t   = (const float*)d_in[10];
  const float* w_f   = (const float*)d_in[11];
  const float* b_f   = (const float*)d_in[12];

  // workspace layout (bytes). Total ~252.2 MiB.
  char* p = (char*)d_ws;
  float* gx    = (float*)(p);                 // 4096*8192*4  = 134217728 (reused by both layers)
  float* hs0f  = (float*)(p + 134217728);     // 4097*2048*4  = 33562624
  float* h1f   = (float*)(p + 167780352);     // 4097*2048*4  = 33562624
  u16*   xb    = (u16*)  (p + 201342976);     // 4096*512*2   = 4194304
  u16*   wb0   = (u16*)  (p + 205537280);     // 8192*512*2   = 8388608
  u16*   wb1   = (u16*)  (p + 213925888);     // 8192*2048*2  = 33554432
  u16*   hs0b  = (u16*)  (p + 247480320);     // 4096*2048*2  = 16777216
  float* bias0 = (float*)(p + 264257536);     // 8192*4
  float* bias1 = (float*)(p + 264290304);     // 8192*4
  int*   flags0= (int*)  (p + 264323072);     // 256*32*4
  int*   flags1= (int*)  (p + 264355840);     // 256*32*4

  // init (re-run every launch => deterministic replay)
  k_zero_f32<<<8, 256, 0, stream>>>(hs0f, HDIM);                 // h0(-1) = 0
  k_zero_f32<<<8, 256, 0, stream>>>(h1f, HDIM);                  // h1(-1) = 0
  k_zero_f32<<<64, 256, 0, stream>>>((float*)flags0, 2 * NBLK * FLAG_STRIDE);
  k_bias_sum<<<GDIM / 256, 256, 0, stream>>>(b_ih0, b_hh0, bias0, GDIM);
  k_bias_sum<<<GDIM / 256, 256, 0, stream>>>(b_ih1, b_hh1, bias1, GDIM);
  k_cvt_bf16<<<1024, 256, 0, stream>>>(x, xb, T_SEQ * INDIM);
  k_cvt_bf16<<<1024, 256, 0, stream>>>(w_ih0, wb0, GDIM * INDIM);
  k_cvt_bf16<<<2048, 256, 0, stream>>>(w_ih1, wb1, GDIM * HDIM);

  // layer 0: gx0 = x @ w_ih0^T + (b_ih0 + b_hh0); then recurrence
  gemm_bt_bias<<<dim3(GDIM / 128, T_SEQ / 128), 256, 0, stream>>>(
      xb, wb0, bias0, gx, T_SEQ, GDIM, INDIM);
  lstm_rec<<<NBLK, 512, 0, stream>>>(gx, w_hh0, hs0f, hs0b, flags0, T_SEQ);

  // layer 1: gx1 = hs0 @ w_ih1^T + (b_ih1 + b_hh1); then recurrence
  gemm_bt_bias<<<dim3(GDIM / 128, T_SEQ / 128), 256, 0, stream>>>(
      hs0b, wb1, bias1, gx, T_SEQ, GDIM, HDIM);
  lstm_rec<<<NBLK, 512, 0, stream>>>(gx, w_hh1, h1f, (u16*)nullptr, flags1, T_SEQ);

  // heads on h1[T]
  k_heads<<<1, 256, 0, stream>>>(h1f + (size_t)T_SEQ * HDIM, w_t, b_t, w_f, b_f,
                                 (float*)d_out);
}

// Round 4
// 302520.728 us; speedup vs baseline: 1.3521x; 1.3521x over previous
//
#include <hip/hip_runtime.h>

typedef __attribute__((ext_vector_type(4))) float f32x4;
typedef __attribute__((ext_vector_type(8))) short short8;
typedef unsigned int u32;
typedef unsigned short u16;

#define T_SEQ 4096
#define HDIM  2048
#define GDIM  8192   // 4*H
#define INDIM 512
#define NBLK  256    // recurrence blocks
#define FLAG_STRIDE 32  // ints -> 128B per flag line

__device__ __forceinline__ u16 f2bf(float x) {
  u32 u = __float_as_uint(x);
  return (u16)((u + 0x7fffu + ((u >> 16) & 1u)) >> 16);  // RNE
}
__device__ __forceinline__ float bflo(u32 u) { return __uint_as_float(u << 16); }
__device__ __forceinline__ float bfhi(u32 u) { return __uint_as_float(u & 0xffff0000u); }

// ---------------- prep kernels ----------------
__global__ void k_zero_f32(float* __restrict__ p, int n) {
  int i = blockIdx.x * blockDim.x + threadIdx.x;
  int st = gridDim.x * blockDim.x;
  for (; i < n; i += st) p[i] = 0.f;
}

__global__ void k_bias_sum(const float* __restrict__ a, const float* __restrict__ b,
                           float* __restrict__ o, int n) {
  int i = blockIdx.x * blockDim.x + threadIdx.x;
  if (i < n) o[i] = a[i] + b[i];
}

__global__ void k_cvt_bf16(const float* __restrict__ in, u16* __restrict__ out, int n) {
  int i = blockIdx.x * blockDim.x + threadIdx.x;
  int st = gridDim.x * blockDim.x;
  for (; i < n; i += st) out[i] = f2bf(in[i]);
}

// Pre-pack W_hh (fp32 [8192][2048]) into the per-block striped bf16 layout that
// lstm_rec stages to LDS with plain coalesced uint4 copies.
// slot = s*512 + tid decodes as: l = slot&63 (lane), r3 = slot>>6,
//   g = r3&3 (k-subgroup), q = (r3>>2)&3 (gate), wv = r3>>4 (wave / h-element).
// gate row = q*2048 + bid*8 + wv ; k = l*32 + g*8 .. +8  (8 bf16 -> uint4)
__global__ __launch_bounds__(512) void k_prep_whh(const float* __restrict__ w,
                                                  uint4* __restrict__ out) {
  const int bid = blockIdx.x;
  const int tid = threadIdx.x;
#pragma unroll
  for (int s = 0; s < 16; ++s) {
    int slot = s * 512 + tid;
    int l = slot & 63, r3 = slot >> 6;
    int g = r3 & 3, q = (r3 >> 2) & 3, wv = r3 >> 4;
    int grow = q * HDIM + bid * 8 + wv;
    const float* src = w + (size_t)grow * HDIM + l * 32 + g * 8;
    uint4 o;
    o.x = (u32)f2bf(src[0]) | ((u32)f2bf(src[1]) << 16);
    o.y = (u32)f2bf(src[2]) | ((u32)f2bf(src[3]) << 16);
    o.z = (u32)f2bf(src[4]) | ((u32)f2bf(src[5]) << 16);
    o.w = (u32)f2bf(src[6]) | ((u32)f2bf(src[7]) << 16);
    out[((size_t)bid * 16 + s) * 512 + tid] = o;
  }
}

// ---------------- bf16 MFMA GEMM:  C[M,N] = A[M,K] * B[N,K]^T + bias[N] ----------------
// 128x128 tile, BK=64, 4 waves (2x2 quadrants of 64x64), 16x16x32 MFMA,
// XOR-swizzled LDS (slot ^= row&7). A is bf16 (AF32=false) or fp32 converted
// in-flight during staging (AF32=true; used for layer-1 reading hs0 fp32).
template <bool AF32>
__global__ __launch_bounds__(256) void gemm_bt_bias(
    const void* __restrict__ Av, const u16* __restrict__ B,
    const float* __restrict__ bias, float* __restrict__ C,
    int M, int N, int K)
{
  __shared__ u16 As[128 * 64];
  __shared__ u16 Bs[128 * 64];
  const int tid = threadIdx.x;
  const int m0 = blockIdx.y * 128;
  const int n0 = blockIdx.x * 128;
  const int w = tid >> 6;
  const int lane = tid & 63;
  const int wm = (w >> 1) * 64, wn = (w & 1) * 64;
  const int lr = lane & 15, lk = lane >> 4;

  f32x4 acc[4][4];
  f32x4 zero = {0.f, 0.f, 0.f, 0.f};
#pragma unroll
  for (int i = 0; i < 4; ++i)
#pragma unroll
    for (int j = 0; j < 4; ++j) acc[i][j] = zero;

  const int r = tid >> 1;           // 0..127 (tile row)
  const int sbase = (tid & 1) * 4;  // slot base (each slot = 8 bf16 = 16B)

  for (int kt = 0; kt < K; kt += 64) {
    uint4 va[4], vb[4];
#pragma unroll
    for (int s = 0; s < 4; ++s) {
      if constexpr (AF32) {
        const float* ga = (const float*)Av + (size_t)(m0 + r) * K + kt + (sbase + s) * 8;
        float4 f0 = *reinterpret_cast<const float4*>(ga);
        float4 f1 = *reinterpret_cast<const float4*>(ga + 4);
        va[s].x = (u32)f2bf(f0.x) | ((u32)f2bf(f0.y) << 16);
        va[s].y = (u32)f2bf(f0.z) | ((u32)f2bf(f0.w) << 16);
        va[s].z = (u32)f2bf(f1.x) | ((u32)f2bf(f1.y) << 16);
        va[s].w = (u32)f2bf(f1.z) | ((u32)f2bf(f1.w) << 16);
      } else {
        const u16* ga = (const u16*)Av + (size_t)(m0 + r) * K + kt + (sbase + s) * 8;
        va[s] = *reinterpret_cast<const uint4*>(ga);
      }
      const u16* gb = B + (size_t)(n0 + r) * K + kt + (sbase + s) * 8;
      vb[s] = *reinterpret_cast<const uint4*>(gb);
    }
    __syncthreads();  // previous iter's reads done before overwrite
#pragma unroll
    for (int s = 0; s < 4; ++s) {
      int ps = (sbase + s) ^ (r & 7);
      *reinterpret_cast<uint4*>(&As[r * 64 + ps * 8]) = va[s];
      *reinterpret_cast<uint4*>(&Bs[r * 64 + ps * 8]) = vb[s];
    }
    __syncthreads();
#pragma unroll
    for (int k32 = 0; k32 < 2; ++k32) {
      short8 af[4], bg[4];
#pragma unroll
      for (int i = 0; i < 4; ++i) {
        int arow = wm + i * 16 + lr;
        int aslot = (k32 * 4 + lk) ^ (arow & 7);
        af[i] = *reinterpret_cast<const short8*>(&As[arow * 64 + aslot * 8]);
        int brow = wn + i * 16 + lr;
        int bslot = (k32 * 4 + lk) ^ (brow & 7);
        bg[i] = *reinterpret_cast<const short8*>(&Bs[brow * 64 + bslot * 8]);
      }
#pragma unroll
      for (int i = 0; i < 4; ++i)
#pragma unroll
        for (int j = 0; j < 4; ++j)
          acc[i][j] = __builtin_amdgcn_mfma_f32_16x16x32_bf16(af[i], bg[j], acc[i][j], 0, 0, 0);
    }
  }

  // epilogue: C/D layout col = lane&15, row = (lane>>4)*4 + reg  [m89-verified]
#pragma unroll
  for (int j = 0; j < 4; ++j) {
    int gcol = n0 + wn + j * 16 + lr;
    float bv = bias[gcol];
#pragma unroll
    for (int i = 0; i < 4; ++i) {
      int grow = m0 + wm + i * 16 + lk * 4;
#pragma unroll
      for (int rr = 0; rr < 4; ++rr)
        C[(size_t)(grow + rr) * N + gcol] = acc[i][j][rr] + bv;
    }
  }
}

// ---------------- persistent LSTM recurrence, LDS-resident weights ----------------
// 256 blocks x 512 threads (8 waves). Wave wv owns h-element bid*8+wv and its 4
// gate rows (i,f,g,o). Weights: bf16 in LDS (128 KiB), staged once from the
// pre-packed wprep layout. h[t]: staged to LDS fp32, XOR-swizzled so both the
// stage write and the stride-32-float reads are conflict-minimal.
//   hT slot for float4-index v (=k/4): (v&7)*64 + ((v>>3) ^ (((v&7)*9)&63))
// Lane l of wave wv: k-chunk = l*32..l*32+32, 4 accumulators (one per gate).
// Reduction: 64-lane butterfly; lane 0 computes gates (c in register), stores h.
// 2 barriers/step; release flag after the store-draining S3 barrier.
// h history rows indexed (t & hmask): full history for layer 0 (hmask=~0>>1),
// depth-4 ring for layer 1 (hmask=3; overwrite-safety: writing h[t+4] requires
// all flags >= t+3 => every block finished reading h[t]).
__global__ __launch_bounds__(512, 1) void lstm_rec(
    const float* __restrict__ gx,    // [T][8192] input contribution (+biases)
    const uint4* __restrict__ wp,    // pre-packed weights [256][16][512] uint4
    float* __restrict__ hhist,       // rows of 2048 floats, row 0 pre-zeroed
    int* __restrict__ flags,         // [NBLK*FLAG_STRIDE], pre-zeroed
    int hmask, int T)
{
  __shared__ uint4 wlds[16 * 512];   // 128 KiB bf16 weights
  __shared__ float4 hT[512];         // 8 KiB swizzled h row
  const int tid = threadIdx.x;
  const int bid = blockIdx.x;
  const int wv = tid >> 6;  // wave -> h element bid*8+wv
  const int l = tid & 63;

  // stage weights once (coalesced; S2 of first iteration orders writes vs reads)
#pragma unroll
  for (int s = 0; s < 16; ++s)
    wlds[s * 512 + tid] = wp[((size_t)bid * 16 + s) * 512 + tid];

  int* myflag = &flags[(tid >> 1) * FLAG_STRIDE];  // producer of h[4*tid .. +4)
  float c = 0.f;                                   // cell state (lane 0 of each wave)

  for (int t = 0; t < T; ++t) {
    // gx prefetch (independent of h[t]; overlaps the poll)
    float gv = 0.f;
    if (l < 4) gv = gx[(size_t)t * GDIM + l * HDIM + bid * 8 + wv];

    // wait for MY h[t] chunk's producer (acquire pairs with its release;
    // per-poll L2-invalidate also freshens the h lines we read next)
    while (__hip_atomic_load(myflag, __ATOMIC_ACQUIRE, __HIP_MEMORY_SCOPE_AGENT) < t)
      __builtin_amdgcn_s_sleep(1);

    // stage h[t] float4 (swizzled write; buffer free per S3 of t-1)
    {
      float4 hv = *reinterpret_cast<const float4*>(
          hhist + (size_t)(t & hmask) * HDIM + tid * 4);
      int G2 = tid & 7, sb = tid >> 3;
      hT[G2 * 64 + (sb ^ ((G2 * 9) & 63))] = hv;
    }
    __syncthreads();  // S2: h staged (also orders initial weight staging)

    float a0 = 0.f, a1 = 0.f, a2 = 0.f, a3 = 0.f;
#pragma unroll
    for (int g = 0; g < 4; ++g) {
      const int G0 = g * 2, G1 = g * 2 + 1;
      float4 h0 = hT[G0 * 64 + (l ^ ((G0 * 9) & 63))];
      float4 h1 = hT[G1 * 64 + (l ^ ((G1 * 9) & 63))];
      uint4 w0 = wlds[(wv * 16 + 0 * 4 + g) * 64 + l];
      uint4 w1 = wlds[(wv * 16 + 1 * 4 + g) * 64 + l];
      uint4 w2 = wlds[(wv * 16 + 2 * 4 + g) * 64 + l];
      uint4 w3 = wlds[(wv * 16 + 3 * 4 + g) * 64 + l];
      a0 += bflo(w0.x) * h0.x + bfhi(w0.x) * h0.y + bflo(w0.y) * h0.z + bfhi(w0.y) * h0.w +
            bflo(w0.z) * h1.x + bfhi(w0.z) * h1.y + bflo(w0.w) * h1.z + bfhi(w0.w) * h1.w;
      a1 += bflo(w1.x) * h0.x + bfhi(w1.x) * h0.y + bflo(w1.y) * h0.z + bfhi(w1.y) * h0.w +
            bflo(w1.z) * h1.x + bfhi(w1.z) * h1.y + bflo(w1.w) * h1.z + bfhi(w1.w) * h1.w;
      a2 += bflo(w2.x) * h0.x + bfhi(w2.x) * h0.y + bflo(w2.y) * h0.z + bfhi(w2.y) * h0.w +
            bflo(w2.z) * h1.x + bfhi(w2.z) * h1.y + bflo(w2.w) * h1.z + bfhi(w2.w) * h1.w;
      a3 += bflo(w3.x) * h0.x + bfhi(w3.x) * h0.y + bflo(w3.y) * h0.z + bfhi(w3.y) * h0.w +
            bflo(w3.z) * h1.x + bfhi(w3.z) * h1.y + bflo(w3.w) * h1.z + bfhi(w3.w) * h1.w;
    }
    // 64-lane butterfly: all lanes end with the 4 gate sums
#pragma unroll
    for (int m = 32; m >= 1; m >>= 1) {
      a0 += __shfl_xor(a0, m);
      a1 += __shfl_xor(a1, m);
      a2 += __shfl_xor(a2, m);
      a3 += __shfl_xor(a3, m);
    }
    float g0 = __shfl(gv, 0), g1 = __shfl(gv, 1), g2 = __shfl(gv, 2), g3 = __shfl(gv, 3);
    if (l == 0) {
      float pi = a0 + g0, pf = a1 + g1, pg = a2 + g2, po = a3 + g3;
      float i_ = 1.f / (1.f + expf(-pi));
      float f_ = 1.f / (1.f + expf(-pf));
      float gg = tanhf(pg);
      float o_ = 1.f / (1.f + expf(-po));
      c = f_ * c + i_ * gg;
      hhist[(size_t)((t + 1) & hmask) * HDIM + bid * 8 + wv] = o_ * tanhf(c);
    }
    __syncthreads();  // S3: all waves' h stores drained (per-wave vmcnt(0))
    if (tid == 0)
      __hip_atomic_store(&flags[bid * FLAG_STRIDE], t + 1, __ATOMIC_RELEASE,
                         __HIP_MEMORY_SCOPE_AGENT);
  }
}

// ---------------- heads: two 2048-dots ----------------
__global__ void k_heads(const float* __restrict__ h, const float* __restrict__ wt,
                        const float* __restrict__ bt, const float* __restrict__ wf,
                        const float* __restrict__ bfp, float* __restrict__ out) {
  int tid = threadIdx.x;  // 256
  float st = 0.f, sf = 0.f;
  for (int i = tid; i < HDIM; i += 256) {
    float hv = h[i];
    st += hv * wt[i];
    sf += hv * wf[i];
  }
#pragma unroll
  for (int m = 32; m >= 1; m >>= 1) {
    st += __shfl_xor(st, m, 64);
    sf += __shfl_xor(sf, m, 64);
  }
  __shared__ float ra[4], rb[4];
  if ((tid & 63) == 0) { ra[tid >> 6] = st; rb[tid >> 6] = sf; }
  __syncthreads();
  if (tid == 0) {
    out[0] = ra[0] + ra[1] + ra[2] + ra[3] + bt[0];
    out[1] = rb[0] + rb[1] + rb[2] + rb[3] + bfp[0];
  }
}

// ---------------- launch ----------------
extern "C" void kernel_launch(void* const* d_in, const int* in_sizes, int n_in,
                              void* d_out, int out_size, void* d_ws, size_t ws_size,
                              hipStream_t stream) {
  const float* x     = (const float*)d_in[0];
  const float* w_ih0 = (const float*)d_in[1];
  const float* w_hh0 = (const float*)d_in[2];
  const float* b_ih0 = (const float*)d_in[3];
  const float* b_hh0 = (const float*)d_in[4];
  const float* w_ih1 = (const float*)d_in[5];
  const float* w_hh1 = (const float*)d_in[6];
  const float* b_ih1 = (const float*)d_in[7];
  const float* b_hh1 = (const float*)d_in[8];
  const float* w_t   = (const float*)d_in[9];
  const float* b_t   = (const float*)d_in[10];
  const float* w_f   = (const float*)d_in[11];
  const float* b_f   = (const float*)d_in[12];

  // workspace layout (bytes), total 247,635,968 B = 236.2 MiB
  // (round-3 crash root cause: 281.2 MB layout overflowed ws; rounds 1-2's
  //  264.4 MB passed => keep well under that.)
  char* p = (char*)d_ws;
  float* gx    = (float*)(p);                 // 134,217,728
  float* hs0f  = (float*)(p + 134217728);     // 4097*2048*4 = 33,562,624
  u16*   xb    = (u16*)  (p + 167780352);     // 4,194,304
  u16*   wb0   = (u16*)  (p + 171974656);     // 8,388,608
  u16*   wb1   = (u16*)  (p + 180363264);     // 33,554,432
  uint4* wprep = (uint4*)(p + 213917696);     // 33,554,432 (reused per layer)
  float* h1r   = (float*)(p + 247472128);     // 4*2048*4 = 32,768 (depth-4 ring)
  float* bias0 = (float*)(p + 247504896);     // 32,768
  float* bias1 = (float*)(p + 247537664);     // 32,768
  int*   flags0= (int*)  (p + 247570432);     // 32,768
  int*   flags1= (int*)  (p + 247603200);     // 32,768

  // init (re-run every launch => deterministic graph replay)
  k_zero_f32<<<8, 256, 0, stream>>>(hs0f, HDIM);        // h0 row 0 = 0
  k_zero_f32<<<32, 256, 0, stream>>>(h1r, 4 * HDIM);    // layer-1 ring = 0
  k_zero_f32<<<64, 256, 0, stream>>>((float*)flags0, 2 * NBLK * FLAG_STRIDE);
  k_bias_sum<<<GDIM / 256, 256, 0, stream>>>(b_ih0, b_hh0, bias0, GDIM);
  k_bias_sum<<<GDIM / 256, 256, 0, stream>>>(b_ih1, b_hh1, bias1, GDIM);
  k_cvt_bf16<<<1024, 256, 0, stream>>>(x, xb, T_SEQ * INDIM);
  k_cvt_bf16<<<1024, 256, 0, stream>>>(w_ih0, wb0, GDIM * INDIM);
  k_cvt_bf16<<<2048, 256, 0, stream>>>(w_ih1, wb1, GDIM * HDIM);

  // layer 0
  k_prep_whh<<<NBLK, 512, 0, stream>>>(w_hh0, wprep);
  gemm_bt_bias<false><<<dim3(GDIM / 128, T_SEQ / 128), 256, 0, stream>>>(
      xb, wb0, bias0, gx, T_SEQ, GDIM, INDIM);
  lstm_rec<<<NBLK, 512, 0, stream>>>(gx, wprep, hs0f, flags0, 0x7fffffff, T_SEQ);

  // layer 1 (A = hs0 fp32 rows 1..T, converted in GEMM staging)
  gemm_bt_bias<true><<<dim3(GDIM / 128, T_SEQ / 128), 256, 0, stream>>>(
      hs0f + HDIM, wb1, bias1, gx, T_SEQ, GDIM, HDIM);
  k_prep_whh<<<NBLK, 512, 0, stream>>>(w_hh1, wprep);
  lstm_rec<<<NBLK, 512, 0, stream>>>(gx, wprep, h1r, flags1, 3, T_SEQ);

  // heads on h1[T] (ring row T&3 == 0)
  k_heads<<<1, 256, 0, stream>>>(h1r + (size_t)(T_SEQ & 3) * HDIM, w_t, b_t, w_f, b_f,
                                 (float*)d_out);
}

// Round 5
// 31394.028 us; speedup vs baseline: 13.0293x; 9.6363x over previous
//
#include <hip/hip_runtime.h>

typedef __attribute__((ext_vector_type(4))) float f32x4;
typedef __attribute__((ext_vector_type(8))) short short8;
typedef unsigned int u32;
typedef unsigned short u16;
typedef unsigned long long u64;

#define T_SEQ 4096
#define HDIM  2048
#define GDIM  8192   // 4*H
#define INDIM 512
#define NBLK  256    // recurrence blocks
#define FLAG_STRIDE 32  // ints -> 128B per flag line

__device__ __forceinline__ u16 f2bf(float x) {
  u32 u = __float_as_uint(x);
  return (u16)((u + 0x7fffu + ((u >> 16) & 1u)) >> 16);  // RNE
}
__device__ __forceinline__ float bflo(u32 u) { return __uint_as_float(u << 16); }
__device__ __forceinline__ float bfhi(u32 u) { return __uint_as_float(u & 0xffff0000u); }

// relaxed agent-scope accessors: single sc-bit instruction, bypasses L1/L2 to
// the die-level coherence point; NO per-access invalidate/writeback (the
// round-1..4 failure: acquire/release in hot loops = cache-maintenance storm).
__device__ __forceinline__ int aload(const int* p) {
  return __hip_atomic_load(p, __ATOMIC_RELAXED, __HIP_MEMORY_SCOPE_AGENT);
}
__device__ __forceinline__ void astore(int* p, int v) {
  __hip_atomic_store(p, v, __ATOMIC_RELAXED, __HIP_MEMORY_SCOPE_AGENT);
}
__device__ __forceinline__ u64 aload64(const u64* p) {
  return __hip_atomic_load(p, __ATOMIC_RELAXED, __HIP_MEMORY_SCOPE_AGENT);
}
__device__ __forceinline__ void astoref(float* p, float v) {
  __hip_atomic_store(p, v, __ATOMIC_RELAXED, __HIP_MEMORY_SCOPE_AGENT);
}

// ---------------- prep kernels ----------------
__global__ void k_zero_f32(float* __restrict__ p, int n) {
  int i = blockIdx.x * blockDim.x + threadIdx.x;
  int st = gridDim.x * blockDim.x;
  for (; i < n; i += st) p[i] = 0.f;
}

__global__ void k_bias_sum(const float* __restrict__ a, const float* __restrict__ b,
                           float* __restrict__ o, int n) {
  int i = blockIdx.x * blockDim.x + threadIdx.x;
  if (i < n) o[i] = a[i] + b[i];
}

__global__ void k_cvt_bf16(const float* __restrict__ in, u16* __restrict__ out, int n) {
  int i = blockIdx.x * blockDim.x + threadIdx.x;
  int st = gridDim.x * blockDim.x;
  for (; i < n; i += st) out[i] = f2bf(in[i]);
}

// Pre-pack W_hh (fp32 [8192][2048]) into the per-block striped bf16 layout that
// lstm_rec stages to LDS with plain coalesced uint4 copies.
// slot = s*512 + tid: l = slot&63 (lane), r3 = slot>>6, g = r3&3 (k-subgroup),
// q = (r3>>2)&3 (gate), wv = r3>>4 (wave / h-element).
// gate row = q*2048 + bid*8 + wv ; k = l*32 + g*8 .. +8  (8 bf16 -> uint4)
__global__ __launch_bounds__(512) void k_prep_whh(const float* __restrict__ w,
                                                  uint4* __restrict__ out) {
  const int bid = blockIdx.x;
  const int tid = threadIdx.x;
#pragma unroll
  for (int s = 0; s < 16; ++s) {
    int slot = s * 512 + tid;
    int l = slot & 63, r3 = slot >> 6;
    int g = r3 & 3, q = (r3 >> 2) & 3, wv = r3 >> 4;
    int grow = q * HDIM + bid * 8 + wv;
    const float* src = w + (size_t)grow * HDIM + l * 32 + g * 8;
    uint4 o;
    o.x = (u32)f2bf(src[0]) | ((u32)f2bf(src[1]) << 16);
    o.y = (u32)f2bf(src[2]) | ((u32)f2bf(src[3]) << 16);
    o.z = (u32)f2bf(src[4]) | ((u32)f2bf(src[5]) << 16);
    o.w = (u32)f2bf(src[6]) | ((u32)f2bf(src[7]) << 16);
    out[((size_t)bid * 16 + s) * 512 + tid] = o;
  }
}

// ---------------- bf16 MFMA GEMM:  C[M,N] = A[M,K] * B[N,K]^T + bias[N] ----------------
template <bool AF32>
__global__ __launch_bounds__(256) void gemm_bt_bias(
    const void* __restrict__ Av, const u16* __restrict__ B,
    const float* __restrict__ bias, float* __restrict__ C,
    int M, int N, int K)
{
  __shared__ u16 As[128 * 64];
  __shared__ u16 Bs[128 * 64];
  const int tid = threadIdx.x;
  const int m0 = blockIdx.y * 128;
  const int n0 = blockIdx.x * 128;
  const int w = tid >> 6;
  const int lane = tid & 63;
  const int wm = (w >> 1) * 64, wn = (w & 1) * 64;
  const int lr = lane & 15, lk = lane >> 4;

  f32x4 acc[4][4];
  f32x4 zero = {0.f, 0.f, 0.f, 0.f};
#pragma unroll
  for (int i = 0; i < 4; ++i)
#pragma unroll
    for (int j = 0; j < 4; ++j) acc[i][j] = zero;

  const int r = tid >> 1;           // 0..127 (tile row)
  const int sbase = (tid & 1) * 4;  // slot base (each slot = 8 bf16 = 16B)

  for (int kt = 0; kt < K; kt += 64) {
    uint4 va[4], vb[4];
#pragma unroll
    for (int s = 0; s < 4; ++s) {
      if constexpr (AF32) {
        const float* ga = (const float*)Av + (size_t)(m0 + r) * K + kt + (sbase + s) * 8;
        float4 f0 = *reinterpret_cast<const float4*>(ga);
        float4 f1 = *reinterpret_cast<const float4*>(ga + 4);
        va[s].x = (u32)f2bf(f0.x) | ((u32)f2bf(f0.y) << 16);
        va[s].y = (u32)f2bf(f0.z) | ((u32)f2bf(f0.w) << 16);
        va[s].z = (u32)f2bf(f1.x) | ((u32)f2bf(f1.y) << 16);
        va[s].w = (u32)f2bf(f1.z) | ((u32)f2bf(f1.w) << 16);
      } else {
        const u16* ga = (const u16*)Av + (size_t)(m0 + r) * K + kt + (sbase + s) * 8;
        va[s] = *reinterpret_cast<const uint4*>(ga);
      }
      const u16* gb = B + (size_t)(n0 + r) * K + kt + (sbase + s) * 8;
      vb[s] = *reinterpret_cast<const uint4*>(gb);
    }
    __syncthreads();  // previous iter's reads done before overwrite
#pragma unroll
    for (int s = 0; s < 4; ++s) {
      int ps = (sbase + s) ^ (r & 7);
      *reinterpret_cast<uint4*>(&As[r * 64 + ps * 8]) = va[s];
      *reinterpret_cast<uint4*>(&Bs[r * 64 + ps * 8]) = vb[s];
    }
    __syncthreads();
#pragma unroll
    for (int k32 = 0; k32 < 2; ++k32) {
      short8 af[4], bg[4];
#pragma unroll
      for (int i = 0; i < 4; ++i) {
        int arow = wm + i * 16 + lr;
        int aslot = (k32 * 4 + lk) ^ (arow & 7);
        af[i] = *reinterpret_cast<const short8*>(&As[arow * 64 + aslot * 8]);
        int brow = wn + i * 16 + lr;
        int bslot = (k32 * 4 + lk) ^ (brow & 7);
        bg[i] = *reinterpret_cast<const short8*>(&Bs[brow * 64 + bslot * 8]);
      }
#pragma unroll
      for (int i = 0; i < 4; ++i)
#pragma unroll
        for (int j = 0; j < 4; ++j)
          acc[i][j] = __builtin_amdgcn_mfma_f32_16x16x32_bf16(af[i], bg[j], acc[i][j], 0, 0, 0);
    }
  }

  // epilogue: C/D layout col = lane&15, row = (lane>>4)*4 + reg  [m89-verified]
#pragma unroll
  for (int j = 0; j < 4; ++j) {
    int gcol = n0 + wn + j * 16 + lr;
    float bv = bias[gcol];
#pragma unroll
    for (int i = 0; i < 4; ++i) {
      int grow = m0 + wm + i * 16 + lk * 4;
#pragma unroll
      for (int rr = 0; rr < 4; ++rr)
        C[(size_t)(grow + rr) * N + gcol] = acc[i][j][rr] + bv;
    }
  }
}

// ---------------- persistent LSTM recurrence, LDS weights + fence-free sync ----
// 256 blocks x 512 threads (8 waves). Wave wv owns h-element bid*8+wv and its 4
// gate rows. Weights bf16 in LDS (128 KiB). Sync per step:
//  - producers: h element stored via relaxed-agent atomic (write-through to the
//    coherence point); B3 (__syncthreads) drains every wave's vmcnt before
//    tid0 relaxed-stores flags[bid]=t+1. No release/writeback instructions.
//  - hub: block 0 wave 0 polls all 256 flags (4/lane, relaxed loads, s_sleep
//    backoff) and publishes epoch=t (one line). All other blocks poll only
//    epoch. B1 (__syncthreads) orders poll-exit before the h loads.
//  - consumers: h row read via relaxed-agent 8B atomic loads (bypass L1/L2 ->
//    always fresh; no invalidates). Normal traffic (gx, weights) stays cached.
__global__ __launch_bounds__(512, 1) void lstm_rec(
    const float* __restrict__ gx,    // [T][8192] input contribution (+biases)
    const uint4* __restrict__ wp,    // pre-packed weights [256][16][512] uint4
    float* __restrict__ hhist,       // rows of 2048 floats, row 0 pre-zeroed
    int* __restrict__ flags,         // [NBLK*FLAG_STRIDE], pre-zeroed
    int* __restrict__ epoch,         // one line, pre-zeroed
    int hmask, int T)
{
  __shared__ uint4 wlds[16 * 512];   // 128 KiB bf16 weights
  __shared__ float4 hT[512];         // 8 KiB swizzled h row
  const int tid = threadIdx.x;
  const int bid = blockIdx.x;
  const int wv = tid >> 6;  // wave -> h element bid*8+wv
  const int l = tid & 63;

  // stage weights once (coalesced; B2 of first iteration orders writes vs reads)
#pragma unroll
  for (int s = 0; s < 16; ++s)
    wlds[s * 512 + tid] = wp[((size_t)bid * 16 + s) * 512 + tid];

  float c = 0.f;  // cell state (lane 0 of each wave)

  for (int t = 0; t < T; ++t) {
    // gx prefetch (cached load, independent of h[t]; overlaps the poll)
    float gv = 0.f;
    if (l < 4) gv = gx[(size_t)t * GDIM + l * HDIM + bid * 8 + wv];

    // ---- wait for h[t] ----
    if (wv == 0) {
      if (bid == 0) {
        // hub: poll all 256 flags, 4 per lane
        const int* f0 = &flags[(l * 4 + 0) * FLAG_STRIDE];
        const int* f1 = &flags[(l * 4 + 1) * FLAG_STRIDE];
        const int* f2 = &flags[(l * 4 + 2) * FLAG_STRIDE];
        const int* f3 = &flags[(l * 4 + 3) * FLAG_STRIDE];
        while (true) {
          int m0 = min(min(aload(f0), aload(f1)), min(aload(f2), aload(f3)));
          if (__all(m0 >= t)) break;
          __builtin_amdgcn_s_sleep(1);
        }
        if (l == 0) astore(epoch, t);  // publish (store issues after loop exit)
      } else {
        while (aload(epoch) < t) __builtin_amdgcn_s_sleep(1);
      }
    }
    __syncthreads();  // B1: h[t] globally ready; orders poll before h loads

    // stage h[t] into LDS (relaxed-agent 8B loads -> coherence point, fresh)
    {
      const u64* hsrc = (const u64*)(hhist + (size_t)(t & hmask) * HDIM);
      u64 d0 = aload64(&hsrc[tid * 2]);
      u64 d1 = aload64(&hsrc[tid * 2 + 1]);
      float4 hv;
      hv.x = __uint_as_float((u32)d0);
      hv.y = __uint_as_float((u32)(d0 >> 32));
      hv.z = __uint_as_float((u32)d1);
      hv.w = __uint_as_float((u32)(d1 >> 32));
      int G2 = tid & 7, sb = tid >> 3;
      hT[G2 * 64 + (sb ^ ((G2 * 9) & 63))] = hv;
    }
    __syncthreads();  // B2: h staged (also orders initial weight staging)

    float a0 = 0.f, a1 = 0.f, a2 = 0.f, a3 = 0.f;
#pragma unroll
    for (int g = 0; g < 4; ++g) {
      const int G0 = g * 2, G1 = g * 2 + 1;
      float4 h0 = hT[G0 * 64 + (l ^ ((G0 * 9) & 63))];
      float4 h1 = hT[G1 * 64 + (l ^ ((G1 * 9) & 63))];
      uint4 w0 = wlds[(wv * 16 + 0 * 4 + g) * 64 + l];
      uint4 w1 = wlds[(wv * 16 + 1 * 4 + g) * 64 + l];
      uint4 w2 = wlds[(wv * 16 + 2 * 4 + g) * 64 + l];
      uint4 w3 = wlds[(wv * 16 + 3 * 4 + g) * 64 + l];
      a0 += bflo(w0.x) * h0.x + bfhi(w0.x) * h0.y + bflo(w0.y) * h0.z + bfhi(w0.y) * h0.w +
            bflo(w0.z) * h1.x + bfhi(w0.z) * h1.y + bflo(w0.w) * h1.z + bfhi(w0.w) * h1.w;
      a1 += bflo(w1.x) * h0.x + bfhi(w1.x) * h0.y + bflo(w1.y) * h0.z + bfhi(w1.y) * h0.w +
            bflo(w1.z) * h1.x + bfhi(w1.z) * h1.y + bflo(w1.w) * h1.z + bfhi(w1.w) * h1.w;
      a2 += bflo(w2.x) * h0.x + bfhi(w2.x) * h0.y + bflo(w2.y) * h0.z + bfhi(w2.y) * h0.w +
            bflo(w2.z) * h1.x + bfhi(w2.z) * h1.y + bflo(w2.w) * h1.z + bfhi(w2.w) * h1.w;
      a3 += bflo(w3.x) * h0.x + bfhi(w3.x) * h0.y + bflo(w3.y) * h0.z + bfhi(w3.y) * h0.w +
            bflo(w3.z) * h1.x + bfhi(w3.z) * h1.y + bflo(w3.w) * h1.z + bfhi(w3.w) * h1.w;
    }
    // 64-lane butterfly: all lanes end with the 4 gate sums
#pragma unroll
    for (int m = 32; m >= 1; m >>= 1) {
      a0 += __shfl_xor(a0, m);
      a1 += __shfl_xor(a1, m);
      a2 += __shfl_xor(a2, m);
      a3 += __shfl_xor(a3, m);
    }
    float g0 = __shfl(gv, 0), g1 = __shfl(gv, 1), g2 = __shfl(gv, 2), g3 = __shfl(gv, 3);
    if (l == 0) {
      float pi = a0 + g0, pf = a1 + g1, pg = a2 + g2, po = a3 + g3;
      float i_ = 1.f / (1.f + expf(-pi));
      float f_ = 1.f / (1.f + expf(-pf));
      float gg = tanhf(pg);
      float o_ = 1.f / (1.f + expf(-po));
      c = f_ * c + i_ * gg;
      // write-through store: at coherence point once this wave's vmcnt drains
      astoref(&hhist[(size_t)((t + 1) & hmask) * HDIM + bid * 8 + wv], o_ * tanhf(c));
    }
    __syncthreads();  // B3: every wave drained vmcnt(0) before s_barrier
    if (tid == 0) astore(&flags[bid * FLAG_STRIDE], t + 1);
  }
}

// ---------------- heads: two 2048-dots ----------------
__global__ void k_heads(const float* __restrict__ h, const float* __restrict__ wt,
                        const float* __restrict__ bt, const float* __restrict__ wf,
                        const float* __restrict__ bfp, float* __restrict__ out) {
  int tid = threadIdx.x;  // 256
  float st = 0.f, sf = 0.f;
  for (int i = tid; i < HDIM; i += 256) {
    float hv = h[i];
    st += hv * wt[i];
    sf += hv * wf[i];
  }
#pragma unroll
  for (int m = 32; m >= 1; m >>= 1) {
    st += __shfl_xor(st, m, 64);
    sf += __shfl_xor(sf, m, 64);
  }
  __shared__ float ra[4], rb[4];
  if ((tid & 63) == 0) { ra[tid >> 6] = st; rb[tid >> 6] = sf; }
  __syncthreads();
  if (tid == 0) {
    out[0] = ra[0] + ra[1] + ra[2] + ra[3] + bt[0];
    out[1] = rb[0] + rb[1] + rb[2] + rb[3] + bfp[0];
  }
}

// ---------------- launch ----------------
extern "C" void kernel_launch(void* const* d_in, const int* in_sizes, int n_in,
                              void* d_out, int out_size, void* d_ws, size_t ws_size,
                              hipStream_t stream) {
  const float* x     = (const float*)d_in[0];
  const float* w_ih0 = (const float*)d_in[1];
  const float* w_hh0 = (const float*)d_in[2];
  const float* b_ih0 = (const float*)d_in[3];
  const float* b_hh0 = (const float*)d_in[4];
  const float* w_ih1 = (const float*)d_in[5];
  const float* w_hh1 = (const float*)d_in[6];
  const float* b_ih1 = (const float*)d_in[7];
  const float* b_hh1 = (const float*)d_in[8];
  const float* w_t   = (const float*)d_in[9];
  const float* b_t   = (const float*)d_in[10];
  const float* w_f   = (const float*)d_in[11];
  const float* b_f   = (const float*)d_in[12];

  // workspace layout (bytes), total ~236.2 MiB (known-good budget)
  char* p = (char*)d_ws;
  float* gx    = (float*)(p);                 // 134,217,728
  float* hs0f  = (float*)(p + 134217728);     // 4097*2048*4 = 33,562,624
  u16*   xb    = (u16*)  (p + 167780352);     // 4,194,304
  u16*   wb0   = (u16*)  (p + 171974656);     // 8,388,608
  u16*   wb1   = (u16*)  (p + 180363264);     // 33,554,432
  uint4* wprep = (uint4*)(p + 213917696);     // 33,554,432 (reused per layer)
  float* h1r   = (float*)(p + 247472128);     // 4*2048*4 = 32,768 (depth-4 ring)
  float* bias0 = (float*)(p + 247504896);     // 32,768
  float* bias1 = (float*)(p + 247537664);     // 32,768
  int*   flags0= (int*)  (p + 247570432);     // 32,768
  int*   flags1= (int*)  (p + 247603200);     // 32,768
  int*   epoch0= (int*)  (p + 247635968);     // 128
  int*   epoch1= (int*)  (p + 247636096);     // 128

  // init (re-run every launch => deterministic graph replay)
  k_zero_f32<<<8, 256, 0, stream>>>(hs0f, HDIM);        // h0 row 0 = 0
  k_zero_f32<<<32, 256, 0, stream>>>(h1r, 4 * HDIM);    // layer-1 ring = 0
  // zero flags0, flags1, epoch0, epoch1 (contiguous)
  k_zero_f32<<<64, 256, 0, stream>>>((float*)flags0, 2 * NBLK * FLAG_STRIDE + 64);
  k_bias_sum<<<GDIM / 256, 256, 0, stream>>>(b_ih0, b_hh0, bias0, GDIM);
  k_bias_sum<<<GDIM / 256, 256, 0, stream>>>(b_ih1, b_hh1, bias1, GDIM);
  k_cvt_bf16<<<1024, 256, 0, stream>>>(x, xb, T_SEQ * INDIM);
  k_cvt_bf16<<<1024, 256, 0, stream>>>(w_ih0, wb0, GDIM * INDIM);
  k_cvt_bf16<<<2048, 256, 0, stream>>>(w_ih1, wb1, GDIM * HDIM);

  // layer 0
  k_prep_whh<<<NBLK, 512, 0, stream>>>(w_hh0, wprep);
  gemm_bt_bias<false><<<dim3(GDIM / 128, T_SEQ / 128), 256, 0, stream>>>(
      xb, wb0, bias0, gx, T_SEQ, GDIM, INDIM);
  lstm_rec<<<NBLK, 512, 0, stream>>>(gx, wprep, hs0f, flags0, epoch0,
                                     0x7fffffff, T_SEQ);

  // layer 1 (A = hs0 fp32 rows 1..T, converted in GEMM staging)
  gemm_bt_bias<true><<<dim3(GDIM / 128, T_SEQ / 128), 256, 0, stream>>>(
      hs0f + HDIM, wb1, bias1, gx, T_SEQ, GDIM, HDIM);
  k_prep_whh<<<NBLK, 512, 0, stream>>>(w_hh1, wprep);
  lstm_rec<<<NBLK, 512, 0, stream>>>(gx, wprep, h1r, flags1, epoch1, 3, T_SEQ);

  // heads on h1[T] (ring row T&3 == 0)
  k_heads<<<1, 256, 0, stream>>>(h1r + (size_t)(T_SEQ & 3) * HDIM, w_t, b_t, w_f, b_f,
                                 (float*)d_out);
}